// Round 16
// baseline (177.450 us; speedup 1.0000x reference)
//
#include <hip/hip_runtime.h>
#include <math.h>

#define EPS 1e-5f

typedef short short8 __attribute__((ext_vector_type(8)));
typedef float f32x4 __attribute__((ext_vector_type(4)));
typedef unsigned short u16;
typedef u16 u16x4 __attribute__((ext_vector_type(4)));

__device__ inline u16 f2bf(float f) {
  union { float f; unsigned u; } x; x.f = f;
  return (u16)((x.u + 0x7fffu + ((x.u >> 16) & 1u)) >> 16);
}
__device__ inline float bf2f(u16 h) {
  union { float f; unsigned u; } x; x.u = ((unsigned)h) << 16;
  return x.f;
}

__device__ inline void gload_lds16(const void* g, void* l) {
  __builtin_amdgcn_global_load_lds((const __attribute__((address_space(1))) void*)g,
                                   (__attribute__((address_space(3))) void*)l, 16, 0, 0);
}

// ---------- zero two buffers in one launch ----------
__global__ void k_zero2(float* __restrict__ a, int na, float* __restrict__ b, int nb) {
  int i = blockIdx.x * 256 + threadIdx.x;
  if (i < na) a[i] = 0.f;
  else if (i - na < nb) b[i - na] = 0.f;
}

// ---------- k_front: [0,nbn) BN1 stats (2x float4 grid-stride) ; [nbn,nbn+neb)
// degree count + edge-position record (exact r11 form) ----------
__global__ __launch_bounds__(256)
void k_front(const float* __restrict__ X, int N, float* __restrict__ pS,
             float* __restrict__ pQ,
             const int* __restrict__ dst, int E, int* __restrict__ deg,
             int* __restrict__ epos, int nbn, int neb) {
  __shared__ float shs[1024], shq[1024];
  int tid = threadIdx.x;
  if ((int)blockIdx.x < nbn) {
    float sum[4] = {0.f, 0.f, 0.f, 0.f}, sq[4] = {0.f, 0.f, 0.f, 0.f};
    size_t total = (size_t)N * 128;
    size_t stride = (size_t)nbn * 512;  // 2 float4s per thread per iteration
    for (size_t i = (size_t)blockIdx.x * 512 + tid; i < total; i += stride) {
      float4 v0 = ((const float4*)X)[i];
      size_t i2 = i + 256;
      bool ok2 = i2 < total;
      float4 v1;
      if (ok2) v1 = ((const float4*)X)[i2];
      sum[0] += v0.x; sq[0] += v0.x * v0.x;
      sum[1] += v0.y; sq[1] += v0.y * v0.y;
      sum[2] += v0.z; sq[2] += v0.z * v0.z;
      sum[3] += v0.w; sq[3] += v0.w * v0.w;
      if (ok2) {
        sum[0] += v1.x; sq[0] += v1.x * v1.x;
        sum[1] += v1.y; sq[1] += v1.y * v1.y;
        sum[2] += v1.z; sq[2] += v1.z * v1.z;
        sum[3] += v1.w; sq[3] += v1.w * v1.w;
      }
    }
#pragma unroll
    for (int i = 0; i < 4; ++i) { shs[tid * 4 + i] = sum[i]; shq[tid * 4 + i] = sq[i]; }
    __syncthreads();
    // col4 = tid&127 (stride and intra-iter offset are both ≡0 mod 128)
    if (tid < 128) {
#pragma unroll
      for (int i = 0; i < 4; ++i) {
        pS[(size_t)blockIdx.x * 512 + tid * 4 + i] = shs[tid * 4 + i] + shs[(tid + 128) * 4 + i];
        pQ[(size_t)blockIdx.x * 512 + tid * 4 + i] = shq[tid * 4 + i] + shq[(tid + 128) * 4 + i];
      }
    }
  } else {
    int b = (int)blockIdx.x - nbn;
    for (int e = b * 256 + tid; e < E; e += neb * 256) {
      int d = dst[e];
      epos[e] = atomicAdd(&deg[d], 1);
    }
  }
}

// ---------- k_mid1: [0,rb) reduce BN1 partials ; [rb,..) scan1 ----------
__global__ __launch_bounds__(256)
void k_mid1(const float* __restrict__ pS, const float* __restrict__ pQ,
            float* __restrict__ s, float* __restrict__ q, int P, int per,
            const int* __restrict__ deg, int N, int* __restrict__ offs,
            int* __restrict__ bsums, float* __restrict__ dinv, int rb) {
  __shared__ int sh[256];
  int t = threadIdx.x;
  if ((int)blockIdx.x < rb) {
    int p0 = blockIdx.x * per;
    int p1 = p0 + per; if (p1 > P) p1 = P;
    float a0 = 0.f, a1 = 0.f, b0 = 0.f, b1 = 0.f;
    for (int p = p0; p < p1; ++p) {
      a0 += pS[(size_t)p * 512 + t];
      a1 += pS[(size_t)p * 512 + t + 256];
      b0 += pQ[(size_t)p * 512 + t];
      b1 += pQ[(size_t)p * 512 + t + 256];
    }
    atomicAdd(&s[t], a0); atomicAdd(&s[t + 256], a1);
    atomicAdd(&q[t], b0); atomicAdd(&q[t + 256], b1);
  } else {
    int bid = (int)blockIdx.x - rb;
    int i = bid * 256 + t;
    int c = (i < N) ? deg[i] : 0;
    if (i < N) dinv[i] = rsqrtf((float)(c + 1));
    int val = c;
    sh[t] = val;
    __syncthreads();
    for (int off = 1; off < 256; off <<= 1) {
      int add = (t >= off) ? sh[t - off] : 0;
      __syncthreads();
      val += add;
      sh[t] = val;
      __syncthreads();
    }
    if (i < N) offs[i] = val - c;
    if (t == 255) bsums[bid] = val;
  }
}

// ---------- k_mid2: [0,wb) WT fold ; [wb,wb+fb) bias fold ; [wb+fb] scan2 ----------
__global__ __launch_bounds__(256)
void k_mid2(const float* __restrict__ s, const float* __restrict__ q,
            const float* __restrict__ gamma, const float* __restrict__ beta,
            const float* __restrict__ W, const float* __restrict__ b,
            u16* __restrict__ WT, float* __restrict__ bp,
            float invN, int lgK, int wb, int fb, int kPerBlock,
            int* __restrict__ bsums, int nb) {
  __shared__ float sh[256];
  __shared__ int shi[256];
  int K = 1 << lgK;
  int t = threadIdx.x;
  if ((int)blockIdx.x < wb) {
    int idx = blockIdx.x * 256 + t;
    int k = idx & (K - 1);
    float mu = s[k] * invN;
    float var = fmaxf(q[k] * invN - mu * mu, 0.f);
    float a = gamma[k] * rsqrtf(var + EPS);
    WT[idx] = f2bf(a * W[(size_t)k * 128 + (idx >> lgK)]);
  } else if ((int)blockIdx.x < wb + fb) {
    int j = t & 127;
    int ksub = t >> 7;
    int k0 = ((int)blockIdx.x - wb) * kPerBlock;
    float acc = 0.f;
    for (int k = k0 + ksub; k < k0 + kPerBlock; k += 2) {
      float mu = s[k] * invN;
      float var = fmaxf(q[k] * invN - mu * mu, 0.f);
      float a = gamma[k] * rsqrtf(var + EPS);
      float c = beta[k] - mu * a;
      acc = fmaf(c, W[(size_t)k * 128 + j], acc);
    }
    sh[t] = acc;
    __syncthreads();
    if (t < 128) {
      float v = sh[t] + sh[t + 128];
      if ((int)blockIdx.x == wb) v += (b ? b[j] : 0.f);
      atomicAdd(&bp[j], v);
    }
  } else {
    if (bsums == nullptr) return;
    int v = (t < nb) ? bsums[t] : 0;
    int val = v;
    shi[t] = val;
    __syncthreads();
    for (int off = 1; off < 256; off <<= 1) {
      int add = (t >= off) ? shi[t - off] : 0;
      __syncthreads();
      val += add;
      shi[t] = val;
      __syncthreads();
    }
    if (t < nb) bsums[t] = val - v;
  }
}

// ---------- k_big: [0,gb) GEMM1 (MFMA bf16, BM=128, A from fp32 X reg-staged) ;
// [gb,..) scatter (atomic-free via epos) ----------
__global__ __launch_bounds__(256)
void k_big(const float* __restrict__ X, const u16* __restrict__ WT,
           const float* __restrict__ bp, u16* __restrict__ Yb,
           float* __restrict__ pS2, float* __restrict__ pQ2, int N,
           const int* __restrict__ src, const int* __restrict__ dst, int E,
           const int* __restrict__ offs, const int* __restrict__ bsums,
           const int* __restrict__ epos, int* __restrict__ col, int gb) {
  __shared__ __align__(16) u16 As[128 * 64];
  __shared__ __align__(16) u16 Bs[128 * 64];
  __shared__ float csum[128], cq[128];
  int tid = threadIdx.x;
  if ((int)blockIdx.x >= gb) {
    int e = ((int)blockIdx.x - gb) * 256 + tid;
    if (e < E) {
      int d = dst[e];
      col[offs[d] + bsums[d >> 8] + epos[e]] = src[e];
    }
    return;
  }
  if (tid < 128) { csum[tid] = 0.f; cq[tid] = 0.f; }
  int lane = tid & 63, wid = tid >> 6;
  int wm = wid & 1, wn = wid >> 1;
  int bRow = blockIdx.x * 128;

  f32x4 acc[4][4];
#pragma unroll
  for (int mi = 0; mi < 4; ++mi)
#pragma unroll
    for (int ni = 0; ni < 4; ++ni) acc[mi][ni] = {0.f, 0.f, 0.f, 0.f};

  for (int k0 = 0; k0 < 512; k0 += 64) {
    // A: fp32 global loads into regs (issue before barrier to overlap)
    float4 ar[4][2];
#pragma unroll
    for (int i = 0; i < 4; ++i) {
      int p = i * 256 + tid;
      int row = p >> 3, slot = p & 7, srs = slot ^ (row & 7);
      int gr = bRow + row; if (gr >= N) gr = N - 1;
      const float4* g = (const float4*)(X + (size_t)gr * 512 + (k0 + srs * 8));
      ar[i][0] = g[0];
      ar[i][1] = g[1];
    }
    __syncthreads();  // previous iteration's LDS readers done
    // B: async global->LDS (pre-swizzled source)
#pragma unroll
    for (int i = 0; i < 4; ++i) {
      int p = i * 256 + tid;
      int row = p >> 3, slot = p & 7, srs = slot ^ (row & 7);
      gload_lds16(WT + (size_t)row * 512 + (k0 + srs * 8), (char*)Bs + p * 16);
    }
    // A: convert + swizzled ds_write_b128
#pragma unroll
    for (int i = 0; i < 4; ++i) {
      int p = i * 256 + tid;
      const float* f0 = (const float*)&ar[i][0];
      short8 v;
#pragma unroll
      for (int j = 0; j < 8; ++j) v[j] = (short)f2bf(f0[j]);
      *(short8*)((char*)As + p * 16) = v;
    }
    __syncthreads();  // drains vmcnt (gload_lds) + lgkmcnt (ds_write)
#pragma unroll
    for (int ks = 0; ks < 2; ++ks) {
      short8 af[4], bfv[4];
#pragma unroll
      for (int mi = 0; mi < 4; ++mi) {
        int row = wm * 64 + mi * 16 + (lane & 15);
        int swz = (ks * 4 + (lane >> 4)) ^ (lane & 7);
        af[mi] = *(const short8*)(As + row * 64 + swz * 8);
      }
#pragma unroll
      for (int ni = 0; ni < 4; ++ni) {
        int row = wn * 64 + ni * 16 + (lane & 15);
        int swz = (ks * 4 + (lane >> 4)) ^ (lane & 7);
        bfv[ni] = *(const short8*)(Bs + row * 64 + swz * 8);
      }
#pragma unroll
      for (int mi = 0; mi < 4; ++mi)
#pragma unroll
        for (int ni = 0; ni < 4; ++ni)
          acc[mi][ni] = __builtin_amdgcn_mfma_f32_16x16x32_bf16(af[mi], bfv[ni], acc[mi][ni], 0, 0, 0);
    }
  }

  float bias[4];
#pragma unroll
  for (int ni = 0; ni < 4; ++ni) bias[ni] = bp[wn * 64 + ni * 16 + (lane & 15)];
  float colp[4] = {0, 0, 0, 0}, colq[4] = {0, 0, 0, 0};
#pragma unroll
  for (int mi = 0; mi < 4; ++mi) {
#pragma unroll
    for (int r = 0; r < 4; ++r) {
      int gr = bRow + wm * 64 + mi * 16 + (lane >> 4) * 4 + r;
      if (gr < N) {
#pragma unroll
        for (int ni = 0; ni < 4; ++ni) {
          float u = fmaxf(acc[mi][ni][r] + bias[ni], 0.f);
          colp[ni] += u;
          colq[ni] += u * u;
          Yb[(size_t)gr * 128 + wn * 64 + ni * 16 + (lane & 15)] = f2bf(u);
        }
      }
    }
  }
#pragma unroll
  for (int ni = 0; ni < 4; ++ni) {
    float a = colp[ni], b = colq[ni];
    a += __shfl_xor(a, 16); a += __shfl_xor(a, 32);
    b += __shfl_xor(b, 16); b += __shfl_xor(b, 32);
    if (lane < 16) {
      atomicAdd(&csum[wn * 64 + ni * 16 + lane], a);
      atomicAdd(&cq[wn * 64 + ni * 16 + lane], b);
    }
  }
  __syncthreads();
  if (tid < 128) {
    pS2[(size_t)blockIdx.x * 128 + tid] = csum[tid];
    pQ2[(size_t)blockIdx.x * 128 + tid] = cq[tid];
  }
}

// ---------- k_agg: [0,rb) reduce gemm1 partials ; [rb,..) gather ----------
__global__ __launch_bounds__(256)
void k_agg(const float* __restrict__ pS, const float* __restrict__ pQ,
           float* __restrict__ s, float* __restrict__ q, int NB, int per,
           const u16* __restrict__ Yb, const int* __restrict__ col,
           const int* __restrict__ offs, const int* __restrict__ bsums,
           const int* __restrict__ deg, const float* __restrict__ dinv,
           u16* __restrict__ Ab, float* __restrict__ scoef, int N, int rb) {
  int tid = threadIdx.x;
  if ((int)blockIdx.x < rb) {
    int col_ = tid & 127;
    const float* src = (tid >= 128) ? pQ : pS;
    int p0 = blockIdx.x * per;
    int p1 = p0 + per; if (p1 > NB) p1 = NB;
    float a = 0.f;
    for (int p = p0; p < p1; ++p) a += src[(size_t)p * 128 + col_];
    atomicAdd((tid >= 128) ? &q[col_] : &s[col_], a);
    return;
  }
  int wid = tid >> 6;
  int lane = tid & 63;
  int d = ((int)blockIdx.x - rb) * 4 + wid;
  if (d >= N) return;
  int p = offs[d] + bsums[d >> 8];
  int c = deg[d];
  float dd = dinv[d];
  float ax, ay;
  {
    unsigned v = ((const unsigned*)(Yb + (size_t)d * 128))[lane];
    ax = dd * bf2f((u16)v);
    ay = dd * bf2f((u16)(v >> 16));
  }
  float sw = 0.f;
  for (int base = 0; base < c; base += 64) {
    int rem = c - base;
    if (rem > 64) rem = 64;
    int sidx = 0;
    float w = 0.f;
    if (lane < rem) {
      sidx = col[p + base + lane];
      w = dinv[sidx];
    }
    sw += w;
    int j = 0;
    for (; j + 7 < rem; j += 8) {
      int ss[8]; float ww[8]; unsigned vv[8];
#pragma unroll
      for (int u = 0; u < 8; ++u) { ss[u] = __shfl(sidx, j + u); ww[u] = __shfl(w, j + u); }
#pragma unroll
      for (int u = 0; u < 8; ++u) vv[u] = ((const unsigned*)(Yb + (size_t)ss[u] * 128))[lane];
#pragma unroll
      for (int u = 0; u < 8; ++u) {
        ax = fmaf(ww[u], bf2f((u16)vv[u]), ax);
        ay = fmaf(ww[u], bf2f((u16)(vv[u] >> 16)), ay);
      }
    }
    for (; j + 3 < rem; j += 4) {
      int s0 = __shfl(sidx, j), s1 = __shfl(sidx, j + 1);
      int s2 = __shfl(sidx, j + 2), s3 = __shfl(sidx, j + 3);
      float w0 = __shfl(w, j), w1 = __shfl(w, j + 1);
      float w2 = __shfl(w, j + 2), w3 = __shfl(w, j + 3);
      unsigned v0 = ((const unsigned*)(Yb + (size_t)s0 * 128))[lane];
      unsigned v1 = ((const unsigned*)(Yb + (size_t)s1 * 128))[lane];
      unsigned v2 = ((const unsigned*)(Yb + (size_t)s2 * 128))[lane];
      unsigned v3 = ((const unsigned*)(Yb + (size_t)s3 * 128))[lane];
      ax = fmaf(w0, bf2f((u16)v0), ax); ay = fmaf(w0, bf2f((u16)(v0 >> 16)), ay);
      ax = fmaf(w1, bf2f((u16)v1), ax); ay = fmaf(w1, bf2f((u16)(v1 >> 16)), ay);
      ax = fmaf(w2, bf2f((u16)v2), ax); ay = fmaf(w2, bf2f((u16)(v2 >> 16)), ay);
      ax = fmaf(w3, bf2f((u16)v3), ax); ay = fmaf(w3, bf2f((u16)(v3 >> 16)), ay);
    }
    for (; j < rem; ++j) {
      int sj = __shfl(sidx, j);
      float wj = __shfl(w, j);
      unsigned v = ((const unsigned*)(Yb + (size_t)sj * 128))[lane];
      ax = fmaf(wj, bf2f((u16)v), ax);
      ay = fmaf(wj, bf2f((u16)(v >> 16)), ay);
    }
  }
#pragma unroll
  for (int off = 32; off; off >>= 1) sw += __shfl_xor(sw, off);
  unsigned o = (unsigned)f2bf(ax * dd) | ((unsigned)f2bf(ay * dd) << 16);
  ((unsigned*)(Ab + (size_t)d * 128))[lane] = o;
  if (lane == 0) scoef[d] = dd * (sw + dd);
}

// ---------- final (MFMA bf16, BK=128; BN2->Wgcn fold computed INLINE) ----------
__global__ __launch_bounds__(256)
void k_final(const u16* __restrict__ Ab,
             const float* __restrict__ s2, const float* __restrict__ q2,
             const float* __restrict__ gamma2, const float* __restrict__ beta2,
             const float* __restrict__ Wg, const float* __restrict__ scoef,
             const float* __restrict__ bg, const float* __restrict__ Wcls,
             const float* __restrict__ bcls, float* __restrict__ out,
             int N, float invN) {
  __shared__ __align__(16) char smem[65536];
  __shared__ float WcS[1280];
  __shared__ float hcS[128], bgS[128], bcS[10];
  __shared__ float aL[128], cL[128], red[256];
  u16* As = (u16*)smem;
  u16* Bs = (u16*)(smem + 32768);
  u16* Tb = (u16*)smem;  // reused after compute: [128][136] bf16
  int tid = threadIdx.x;
  for (int i = tid; i < 1280; i += 256) WcS[i] = Wcls[i];
  if (tid < 128) bgS[tid] = bg[tid];
  if (tid < 10) bcS[tid] = bcls[tid];
  // BN2 fold coefficients
  if (tid < 128) {
    float mu = s2[tid] * invN;
    float var = fmaxf(q2[tid] * invN - mu * mu, 0.f);
    float a = gamma2[tid] * rsqrtf(var + EPS);
    aL[tid] = a;
    cL[tid] = beta2[tid] - mu * a;
  }
  int lane = tid & 63, wid = tid >> 6;
  int wm = wid & 1, wn = wid >> 1;
  int bRow = blockIdx.x * 128;

  // A tile via async gload (independent of fold coefficients)
#pragma unroll
  for (int i = 0; i < 8; ++i) {
    int p = i * 256 + tid;
    int row = p >> 4, slot = p & 15, srs = slot ^ (row & 7);
    int gr = bRow + row; if (gr >= N) gr = N - 1;
    gload_lds16(Ab + (size_t)gr * 128 + srs * 8, (char*)As + p * 16);
  }
  __syncthreads();  // aL/cL visible (also drains As gloads)

  // B tile: inline fold a[k]*Wg[k][j], same swizzled layout the gload path used
#pragma unroll
  for (int i = 0; i < 8; ++i) {
    int p = i * 256 + tid;
    int row = p >> 4, slot = p & 15, srs = slot ^ (row & 7);
    short8 v;
#pragma unroll
    for (int jj = 0; jj < 8; ++jj) {
      int k = srs * 8 + jj;
      v[jj] = (short)f2bf(aL[k] * Wg[(size_t)k * 128 + row]);
    }
    *(short8*)((char*)Bs + p * 16) = v;
  }
  // hconst[j] = sum_k c[k]*Wg[k][j] (two k-halves per j)
  {
    int j = tid & 127, half = tid >> 7;
    float hacc = 0.f;
    for (int k = half * 64; k < half * 64 + 64; ++k)
      hacc = fmaf(cL[k], Wg[(size_t)k * 128 + j], hacc);
    red[tid] = hacc;
  }
  f32x4 acc[4][4];
#pragma unroll
  for (int mi = 0; mi < 4; ++mi)
#pragma unroll
    for (int ni = 0; ni < 4; ++ni) acc[mi][ni] = {0.f, 0.f, 0.f, 0.f};
  __syncthreads();
  if (tid < 128) hcS[tid] = red[tid] + red[tid + 128];
  __syncthreads();
#pragma unroll
  for (int ks = 0; ks < 4; ++ks) {
    short8 af[4], bfv[4];
#pragma unroll
    for (int mi = 0; mi < 4; ++mi) {
      int row = wm * 64 + mi * 16 + (lane & 15);
      int swz = (ks * 4 + (lane >> 4)) ^ (lane & 7);
      af[mi] = *(const short8*)(As + row * 128 + swz * 8);
    }
#pragma unroll
    for (int ni = 0; ni < 4; ++ni) {
      int row = wn * 64 + ni * 16 + (lane & 15);
      int swz = (ks * 4 + (lane >> 4)) ^ (lane & 7);
      bfv[ni] = *(const short8*)(Bs + row * 128 + swz * 8);
    }
#pragma unroll
    for (int mi = 0; mi < 4; ++mi)
#pragma unroll
      for (int ni = 0; ni < 4; ++ni)
        acc[mi][ni] = __builtin_amdgcn_mfma_f32_16x16x32_bf16(af[mi], bfv[ni], acc[mi][ni], 0, 0, 0);
  }
  __syncthreads();  // all LDS reads done before Tb overwrite

  float hcv[4], bgv[4];
#pragma unroll
  for (int ni = 0; ni < 4; ++ni) {
    int n = wn * 64 + ni * 16 + (lane & 15);
    hcv[ni] = hcS[n];
    bgv[ni] = bgS[n];
  }
#pragma unroll
  for (int mi = 0; mi < 4; ++mi) {
#pragma unroll
    for (int r = 0; r < 4; ++r) {
      int m = wm * 64 + mi * 16 + (lane >> 4) * 4 + r;
      int gr = bRow + m;
      float sc = (gr < N) ? scoef[gr] : 0.f;
#pragma unroll
      for (int ni = 0; ni < 4; ++ni) {
        float u = fmaxf(acc[mi][ni][r] + hcv[ni] * sc + bgv[ni], 0.f);
        Tb[m * 136 + wn * 64 + ni * 16 + (lane & 15)] = f2bf(u);
      }
    }
  }
  __syncthreads();

  int r2 = tid >> 1, qd = tid & 1;
  float part[10];
#pragma unroll
  for (int t = 0; t < 10; ++t) part[t] = 0.f;
  for (int jj = 0; jj < 64; ++jj) {
    int j = qd * 64 + jj;
    float a = bf2f(Tb[r2 * 136 + j]);
#pragma unroll
    for (int t = 0; t < 10; ++t) part[t] = fmaf(a, WcS[j * 10 + t], part[t]);
  }
#pragma unroll
  for (int t = 0; t < 10; ++t) part[t] += __shfl_xor(part[t], 1);
  int gr = bRow + r2;
  if (qd == 0 && gr < N) {
    float l[10], m = -1e30f;
#pragma unroll
    for (int t = 0; t < 10; ++t) {
      l[t] = part[t] + bcS[t];
      m = fmaxf(m, l[t]);
    }
    float se = 0.f;
#pragma unroll
    for (int t = 0; t < 10; ++t) se += expf(l[t] - m);
    float lse = m + logf(se);
#pragma unroll
    for (int t = 0; t < 10; ++t) out[(size_t)gr * 10 + t] = l[t] - lse;
  }
}

// ---------------------------------------------------------------------------
extern "C" void kernel_launch(void* const* d_in, const int* in_sizes, int n_in,
                              void* d_out, int out_size, void* d_ws, size_t ws_size,
                              hipStream_t stream) {
  const float* X = (const float*)d_in[0];
  const int* ei = (const int*)d_in[2];
  const float* gamma1 = (const float*)d_in[3];
  const float* beta1 = (const float*)d_in[4];
  const float* Wmlp = (const float*)d_in[5];
  const float* bmlp = (const float*)d_in[6];
  const float* gamma2 = (const float*)d_in[7];
  const float* beta2 = (const float*)d_in[8];
  const float* Wgcn = (const float*)d_in[9];
  const float* bgcn = (const float*)d_in[10];
  const float* Wcls = (const float*)d_in[11];
  const float* bcls = (const float*)d_in[12];
  float* out = (float*)d_out;

  const int N = in_sizes[0] / 512;
  const int E = in_sizes[2] / 2;
  const float invN = 1.0f / (float)N;

  char* ws = (char*)d_ws;
  float* s1 = (float*)(ws + 0);            // 512
  float* q1 = (float*)(ws + 2048);         // 512
  float* s2 = (float*)(ws + 4096);         // 128
  float* q2 = (float*)(ws + 4608);         // 128
  float* b1p = (float*)(ws + 5120);        // 128
  u16* W1bT = (u16*)(ws + 8192);           // 128*512 bf16
  int* bsums = (int*)(ws + 172032);        // 256
  int* deg = (int*)(ws + 173056);          // N -> 373056
  int* offs = (int*)(ws + 373056);         // N -> 573056
  float* dinv = (float*)(ws + 573056);     // N -> 773056
  float* scoef = (float*)(ws + 773056);    // N -> 973056
  int* col = (int*)(ws + 973056);          // E -> 4173056
  int* epos = (int*)(ws + 4173056);        // E -> 7373056
  u16* Yb = (u16*)(ws + 7373056);          // N*128 bf16 -> 20173056
  u16* Ab = (u16*)(ws + 20173056);         // N*128 bf16 -> 32973056
  float* pS1 = (float*)(ws + 32973056);    // 1280*512 -> 35594496
  float* pQ1 = (float*)(ws + 35594496);    // 1280*512 -> 38215936
  float* pS2 = (float*)(ws + 38215936);    // 391*128 -> 38416128
  float* pQ2 = (float*)(ws + 38416128);    // 391*128 -> 38616320
  (void)ws_size; (void)n_in; (void)out_size;

  const int* esrc = ei;
  const int* edst = ei + E;
  int nb = (N + 255) / 256;   // 196
  int eb = (E + 255) / 256;   // 3125
  int gb = (N + 127) / 128;   // 391
  const int NBN = 1280;       // bn-stream blocks (r11 proven config)
  const int NEB = 768;        // degree blocks (grid-stride)

  // 1) zero stats+b1p (1280+... 1536 floats covers s1,q1,s2,q2,b1p,pad) and deg
  k_zero2<<<(1536 + N + 255) / 256, 256, 0, stream>>>(s1, 1536, (float*)deg, N);
  // 2) bn1 stats || degree count + epos record (co-resident)
  k_front<<<NBN + NEB, 256, 0, stream>>>(X, N, pS1, pQ1, edst, E, deg, epos, NBN, NEB);
  // 3) reduce bn1 partials || block-local scan
  k_mid1<<<16 + nb, 256, 0, stream>>>(pS1, pQ1, s1, q1, NBN, 80, deg, N, offs, bsums, dinv, 16);
  // 4) fold1 (WT + bias) || scan2
  k_mid2<<<272 + 1, 256, 0, stream>>>(s1, q1, gamma1, beta1, Wmlp, bmlp, W1bT, b1p,
                                      invN, 9, 256, 16, 32, bsums, nb);
  // 5) gemm1 (BM=128) || scatter (atomic-free)
  k_big<<<gb + eb, 256, 0, stream>>>(X, W1bT, b1p, Yb, pS2, pQ2, N,
                                     esrc, edst, E, offs, bsums, epos, col, gb);
  // 6) reduce gemm1 partials || gather
  k_agg<<<8 + (N + 3) / 4, 256, 0, stream>>>(pS2, pQ2, s2, q2, gb, (gb + 7) / 8,
                                             Yb, col, offs, bsums, deg, dinv, Ab, scoef, N, 8);
  // 7) final (BN2 fold inline — fold2 launch eliminated)
  k_final<<<gb, 256, 0, stream>>>(Ab, s2, q2, gamma2, beta2, Wgcn, scoef, bgcn,
                                  Wcls, bcls, out, N, invN);
}

// Round 17
// 166.502 us; speedup vs baseline: 1.0658x; 1.0658x over previous
//
#include <hip/hip_runtime.h>
#include <math.h>

#define EPS 1e-5f

typedef short short8 __attribute__((ext_vector_type(8)));
typedef float f32x4 __attribute__((ext_vector_type(4)));
typedef unsigned short u16;
typedef u16 u16x4 __attribute__((ext_vector_type(4)));

__device__ inline u16 f2bf(float f) {
  union { float f; unsigned u; } x; x.f = f;
  return (u16)((x.u + 0x7fffu + ((x.u >> 16) & 1u)) >> 16);
}
__device__ inline float bf2f(u16 h) {
  union { float f; unsigned u; } x; x.u = ((unsigned)h) << 16;
  return x.f;
}

__device__ inline void gload_lds16(const void* g, void* l) {
  __builtin_amdgcn_global_load_lds((const __attribute__((address_space(1))) void*)g,
                                   (__attribute__((address_space(3))) void*)l, 16, 0, 0);
}

// ---------- zero two buffers in one launch ----------
__global__ void k_zero2(float* __restrict__ a, int na, float* __restrict__ b, int nb) {
  int i = blockIdx.x * 256 + threadIdx.x;
  if (i < na) a[i] = 0.f;
  else if (i - na < nb) b[i - na] = 0.f;
}

// ---------- k_front: [0,nbn) BN1 stats (2x float4 grid-stride) ; [nbn,nbn+neb)
// degree count + edge-position record ----------
__global__ __launch_bounds__(256)
void k_front(const float* __restrict__ X, int N, float* __restrict__ pS,
             float* __restrict__ pQ,
             const int* __restrict__ dst, int E, int* __restrict__ deg,
             int* __restrict__ epos, int nbn, int neb) {
  __shared__ float shs[1024], shq[1024];
  int tid = threadIdx.x;
  if ((int)blockIdx.x < nbn) {
    float sum[4] = {0.f, 0.f, 0.f, 0.f}, sq[4] = {0.f, 0.f, 0.f, 0.f};
    size_t total = (size_t)N * 128;
    size_t stride = (size_t)nbn * 512;  // 2 float4s per thread per iteration
    for (size_t i = (size_t)blockIdx.x * 512 + tid; i < total; i += stride) {
      float4 v0 = ((const float4*)X)[i];
      size_t i2 = i + 256;
      bool ok2 = i2 < total;
      float4 v1;
      if (ok2) v1 = ((const float4*)X)[i2];
      sum[0] += v0.x; sq[0] += v0.x * v0.x;
      sum[1] += v0.y; sq[1] += v0.y * v0.y;
      sum[2] += v0.z; sq[2] += v0.z * v0.z;
      sum[3] += v0.w; sq[3] += v0.w * v0.w;
      if (ok2) {
        sum[0] += v1.x; sq[0] += v1.x * v1.x;
        sum[1] += v1.y; sq[1] += v1.y * v1.y;
        sum[2] += v1.z; sq[2] += v1.z * v1.z;
        sum[3] += v1.w; sq[3] += v1.w * v1.w;
      }
    }
#pragma unroll
    for (int i = 0; i < 4; ++i) { shs[tid * 4 + i] = sum[i]; shq[tid * 4 + i] = sq[i]; }
    __syncthreads();
    // col4 = tid&127 (stride and intra-iter offset are both ≡0 mod 128)
    if (tid < 128) {
#pragma unroll
      for (int i = 0; i < 4; ++i) {
        pS[(size_t)blockIdx.x * 512 + tid * 4 + i] = shs[tid * 4 + i] + shs[(tid + 128) * 4 + i];
        pQ[(size_t)blockIdx.x * 512 + tid * 4 + i] = shq[tid * 4 + i] + shq[(tid + 128) * 4 + i];
      }
    }
  } else {
    int b = (int)blockIdx.x - nbn;
    for (int e = b * 256 + tid; e < E; e += neb * 256) {
      int d = dst[e];
      epos[e] = atomicAdd(&deg[d], 1);
    }
  }
}

// ---------- k_mid1: [0,rb) reduce BN1 partials ; [rb,..) scan1 ----------
__global__ __launch_bounds__(256)
void k_mid1(const float* __restrict__ pS, const float* __restrict__ pQ,
            float* __restrict__ s, float* __restrict__ q, int P, int per,
            const int* __restrict__ deg, int N, int* __restrict__ offs,
            int* __restrict__ bsums, float* __restrict__ dinv, int rb) {
  __shared__ int sh[256];
  int t = threadIdx.x;
  if ((int)blockIdx.x < rb) {
    int p0 = blockIdx.x * per;
    int p1 = p0 + per; if (p1 > P) p1 = P;
    float a0 = 0.f, a1 = 0.f, b0 = 0.f, b1 = 0.f;
    for (int p = p0; p < p1; ++p) {
      a0 += pS[(size_t)p * 512 + t];
      a1 += pS[(size_t)p * 512 + t + 256];
      b0 += pQ[(size_t)p * 512 + t];
      b1 += pQ[(size_t)p * 512 + t + 256];
    }
    atomicAdd(&s[t], a0); atomicAdd(&s[t + 256], a1);
    atomicAdd(&q[t], b0); atomicAdd(&q[t + 256], b1);
  } else {
    int bid = (int)blockIdx.x - rb;
    int i = bid * 256 + t;
    int c = (i < N) ? deg[i] : 0;
    if (i < N) dinv[i] = rsqrtf((float)(c + 1));
    int val = c;
    sh[t] = val;
    __syncthreads();
    for (int off = 1; off < 256; off <<= 1) {
      int add = (t >= off) ? sh[t - off] : 0;
      __syncthreads();
      val += add;
      sh[t] = val;
      __syncthreads();
    }
    if (i < N) offs[i] = val - c;
    if (t == 255) bsums[bid] = val;
  }
}

// ---------- k_mid2: [0,wb) WT fold ; [wb,wb+fb) bias fold ; [wb+fb] scan2 ----------
__global__ __launch_bounds__(256)
void k_mid2(const float* __restrict__ s, const float* __restrict__ q,
            const float* __restrict__ gamma, const float* __restrict__ beta,
            const float* __restrict__ W, const float* __restrict__ b,
            u16* __restrict__ WT, float* __restrict__ bp,
            float invN, int lgK, int wb, int fb, int kPerBlock,
            int* __restrict__ bsums, int nb) {
  __shared__ float sh[256];
  __shared__ int shi[256];
  int K = 1 << lgK;
  int t = threadIdx.x;
  if ((int)blockIdx.x < wb) {
    int idx = blockIdx.x * 256 + t;
    int k = idx & (K - 1);
    float mu = s[k] * invN;
    float var = fmaxf(q[k] * invN - mu * mu, 0.f);
    float a = gamma[k] * rsqrtf(var + EPS);
    WT[idx] = f2bf(a * W[(size_t)k * 128 + (idx >> lgK)]);
  } else if ((int)blockIdx.x < wb + fb) {
    int j = t & 127;
    int ksub = t >> 7;
    int k0 = ((int)blockIdx.x - wb) * kPerBlock;
    float acc = 0.f;
    for (int k = k0 + ksub; k < k0 + kPerBlock; k += 2) {
      float mu = s[k] * invN;
      float var = fmaxf(q[k] * invN - mu * mu, 0.f);
      float a = gamma[k] * rsqrtf(var + EPS);
      float c = beta[k] - mu * a;
      acc = fmaf(c, W[(size_t)k * 128 + j], acc);
    }
    sh[t] = acc;
    __syncthreads();
    if (t < 128) {
      float v = sh[t] + sh[t + 128];
      if ((int)blockIdx.x == wb) v += (b ? b[j] : 0.f);
      atomicAdd(&bp[j], v);
    }
  } else {
    if (bsums == nullptr) return;
    int v = (t < nb) ? bsums[t] : 0;
    int val = v;
    shi[t] = val;
    __syncthreads();
    for (int off = 1; off < 256; off <<= 1) {
      int add = (t >= off) ? shi[t - off] : 0;
      __syncthreads();
      val += add;
      shi[t] = val;
      __syncthreads();
    }
    if (t < nb) bsums[t] = val - v;
  }
}

// ---------- k_big: [0,gb) GEMM1 (MFMA bf16, BM=128, A from fp32 X reg-staged) ;
// [gb,..) scatter (atomic-free via epos) ----------
__global__ __launch_bounds__(256)
void k_big(const float* __restrict__ X, const u16* __restrict__ WT,
           const float* __restrict__ bp, u16* __restrict__ Yb,
           float* __restrict__ pS2, float* __restrict__ pQ2, int N,
           const int* __restrict__ src, const int* __restrict__ dst, int E,
           const int* __restrict__ offs, const int* __restrict__ bsums,
           const int* __restrict__ epos, int* __restrict__ col, int gb) {
  __shared__ __align__(16) u16 As[128 * 64];
  __shared__ __align__(16) u16 Bs[128 * 64];
  __shared__ float csum[128], cq[128];
  int tid = threadIdx.x;
  if ((int)blockIdx.x >= gb) {
    int e = ((int)blockIdx.x - gb) * 256 + tid;
    if (e < E) {
      int d = dst[e];
      col[offs[d] + bsums[d >> 8] + epos[e]] = src[e];
    }
    return;
  }
  if (tid < 128) { csum[tid] = 0.f; cq[tid] = 0.f; }
  int lane = tid & 63, wid = tid >> 6;
  int wm = wid & 1, wn = wid >> 1;
  int bRow = blockIdx.x * 128;

  f32x4 acc[4][4];
#pragma unroll
  for (int mi = 0; mi < 4; ++mi)
#pragma unroll
    for (int ni = 0; ni < 4; ++ni) acc[mi][ni] = {0.f, 0.f, 0.f, 0.f};

  for (int k0 = 0; k0 < 512; k0 += 64) {
    // A: fp32 global loads into regs (issue before barrier to overlap)
    float4 ar[4][2];
#pragma unroll
    for (int i = 0; i < 4; ++i) {
      int p = i * 256 + tid;
      int row = p >> 3, slot = p & 7, srs = slot ^ (row & 7);
      int gr = bRow + row; if (gr >= N) gr = N - 1;
      const float4* g = (const float4*)(X + (size_t)gr * 512 + (k0 + srs * 8));
      ar[i][0] = g[0];
      ar[i][1] = g[1];
    }
    __syncthreads();  // previous iteration's LDS readers done
    // B: async global->LDS (pre-swizzled source)
#pragma unroll
    for (int i = 0; i < 4; ++i) {
      int p = i * 256 + tid;
      int row = p >> 3, slot = p & 7, srs = slot ^ (row & 7);
      gload_lds16(WT + (size_t)row * 512 + (k0 + srs * 8), (char*)Bs + p * 16);
    }
    // A: convert + swizzled ds_write_b128
#pragma unroll
    for (int i = 0; i < 4; ++i) {
      int p = i * 256 + tid;
      const float* f0 = (const float*)&ar[i][0];
      short8 v;
#pragma unroll
      for (int j = 0; j < 8; ++j) v[j] = (short)f2bf(f0[j]);
      *(short8*)((char*)As + p * 16) = v;
    }
    __syncthreads();  // drains vmcnt (gload_lds) + lgkmcnt (ds_write)
#pragma unroll
    for (int ks = 0; ks < 2; ++ks) {
      short8 af[4], bfv[4];
#pragma unroll
      for (int mi = 0; mi < 4; ++mi) {
        int row = wm * 64 + mi * 16 + (lane & 15);
        int swz = (ks * 4 + (lane >> 4)) ^ (lane & 7);
        af[mi] = *(const short8*)(As + row * 64 + swz * 8);
      }
#pragma unroll
      for (int ni = 0; ni < 4; ++ni) {
        int row = wn * 64 + ni * 16 + (lane & 15);
        int swz = (ks * 4 + (lane >> 4)) ^ (lane & 7);
        bfv[ni] = *(const short8*)(Bs + row * 64 + swz * 8);
      }
#pragma unroll
      for (int mi = 0; mi < 4; ++mi)
#pragma unroll
        for (int ni = 0; ni < 4; ++ni)
          acc[mi][ni] = __builtin_amdgcn_mfma_f32_16x16x32_bf16(af[mi], bfv[ni], acc[mi][ni], 0, 0, 0);
    }
  }

  float bias[4];
#pragma unroll
  for (int ni = 0; ni < 4; ++ni) bias[ni] = bp[wn * 64 + ni * 16 + (lane & 15)];
  float colp[4] = {0, 0, 0, 0}, colq[4] = {0, 0, 0, 0};
#pragma unroll
  for (int mi = 0; mi < 4; ++mi) {
#pragma unroll
    for (int r = 0; r < 4; ++r) {
      int gr = bRow + wm * 64 + mi * 16 + (lane >> 4) * 4 + r;
      if (gr < N) {
#pragma unroll
        for (int ni = 0; ni < 4; ++ni) {
          float u = fmaxf(acc[mi][ni][r] + bias[ni], 0.f);
          colp[ni] += u;
          colq[ni] += u * u;
          Yb[(size_t)gr * 128 + wn * 64 + ni * 16 + (lane & 15)] = f2bf(u);
        }
      }
    }
  }
#pragma unroll
  for (int ni = 0; ni < 4; ++ni) {
    float a = colp[ni], b = colq[ni];
    a += __shfl_xor(a, 16); a += __shfl_xor(a, 32);
    b += __shfl_xor(b, 16); b += __shfl_xor(b, 32);
    if (lane < 16) {
      atomicAdd(&csum[wn * 64 + ni * 16 + lane], a);
      atomicAdd(&cq[wn * 64 + ni * 16 + lane], b);
    }
  }
  __syncthreads();
  if (tid < 128) {
    pS2[(size_t)blockIdx.x * 128 + tid] = csum[tid];
    pQ2[(size_t)blockIdx.x * 128 + tid] = cq[tid];
  }
}

// ---------- k_agg: [0,rb) reduce gemm1 partials ; [rb,..) gather ----------
__global__ __launch_bounds__(256)
void k_agg(const float* __restrict__ pS, const float* __restrict__ pQ,
           float* __restrict__ s, float* __restrict__ q, int NB, int per,
           const u16* __restrict__ Yb, const int* __restrict__ col,
           const int* __restrict__ offs, const int* __restrict__ bsums,
           const int* __restrict__ deg, const float* __restrict__ dinv,
           u16* __restrict__ Ab, float* __restrict__ scoef, int N, int rb) {
  int tid = threadIdx.x;
  if ((int)blockIdx.x < rb) {
    int col_ = tid & 127;
    const float* src = (tid >= 128) ? pQ : pS;
    int p0 = blockIdx.x * per;
    int p1 = p0 + per; if (p1 > NB) p1 = NB;
    float a = 0.f;
    for (int p = p0; p < p1; ++p) a += src[(size_t)p * 128 + col_];
    atomicAdd((tid >= 128) ? &q[col_] : &s[col_], a);
    return;
  }
  int wid = tid >> 6;
  int lane = tid & 63;
  int d = ((int)blockIdx.x - rb) * 4 + wid;
  if (d >= N) return;
  int p = offs[d] + bsums[d >> 8];
  int c = deg[d];
  float dd = dinv[d];
  float ax, ay;
  {
    unsigned v = ((const unsigned*)(Yb + (size_t)d * 128))[lane];
    ax = dd * bf2f((u16)v);
    ay = dd * bf2f((u16)(v >> 16));
  }
  float sw = 0.f;
  for (int base = 0; base < c; base += 64) {
    int rem = c - base;
    if (rem > 64) rem = 64;
    int sidx = 0;
    float w = 0.f;
    if (lane < rem) {
      sidx = col[p + base + lane];
      w = dinv[sidx];
    }
    sw += w;
    int j = 0;
    for (; j + 7 < rem; j += 8) {
      int ss[8]; float ww[8]; unsigned vv[8];
#pragma unroll
      for (int u = 0; u < 8; ++u) { ss[u] = __shfl(sidx, j + u); ww[u] = __shfl(w, j + u); }
#pragma unroll
      for (int u = 0; u < 8; ++u) vv[u] = ((const unsigned*)(Yb + (size_t)ss[u] * 128))[lane];
#pragma unroll
      for (int u = 0; u < 8; ++u) {
        ax = fmaf(ww[u], bf2f((u16)vv[u]), ax);
        ay = fmaf(ww[u], bf2f((u16)(vv[u] >> 16)), ay);
      }
    }
    for (; j + 3 < rem; j += 4) {
      int s0 = __shfl(sidx, j), s1 = __shfl(sidx, j + 1);
      int s2 = __shfl(sidx, j + 2), s3 = __shfl(sidx, j + 3);
      float w0 = __shfl(w, j), w1 = __shfl(w, j + 1);
      float w2 = __shfl(w, j + 2), w3 = __shfl(w, j + 3);
      unsigned v0 = ((const unsigned*)(Yb + (size_t)s0 * 128))[lane];
      unsigned v1 = ((const unsigned*)(Yb + (size_t)s1 * 128))[lane];
      unsigned v2 = ((const unsigned*)(Yb + (size_t)s2 * 128))[lane];
      unsigned v3 = ((const unsigned*)(Yb + (size_t)s3 * 128))[lane];
      ax = fmaf(w0, bf2f((u16)v0), ax); ay = fmaf(w0, bf2f((u16)(v0 >> 16)), ay);
      ax = fmaf(w1, bf2f((u16)v1), ax); ay = fmaf(w1, bf2f((u16)(v1 >> 16)), ay);
      ax = fmaf(w2, bf2f((u16)v2), ax); ay = fmaf(w2, bf2f((u16)(v2 >> 16)), ay);
      ax = fmaf(w3, bf2f((u16)v3), ax); ay = fmaf(w3, bf2f((u16)(v3 >> 16)), ay);
    }
    for (; j < rem; ++j) {
      int sj = __shfl(sidx, j);
      float wj = __shfl(w, j);
      unsigned v = ((const unsigned*)(Yb + (size_t)sj * 128))[lane];
      ax = fmaf(wj, bf2f((u16)v), ax);
      ay = fmaf(wj, bf2f((u16)(v >> 16)), ay);
    }
  }
#pragma unroll
  for (int off = 32; off; off >>= 1) sw += __shfl_xor(sw, off);
  unsigned o = (unsigned)f2bf(ax * dd) | ((unsigned)f2bf(ay * dd) << 16);
  ((unsigned*)(Ab + (size_t)d * 128))[lane] = o;
  if (lane == 0) scoef[d] = dd * (sw + dd);
}

// ---------- final (MFMA bf16, BK=128 single pass) ----------
__global__ __launch_bounds__(256)
void k_final(const u16* __restrict__ Ab, const u16* __restrict__ W2T,
             const float* __restrict__ hc, const float* __restrict__ scoef,
             const float* __restrict__ bg, const float* __restrict__ Wcls,
             const float* __restrict__ bcls, float* __restrict__ out, int N) {
  __shared__ __align__(16) char smem[65536];
  __shared__ float WcS[1280];
  __shared__ float hcS[128], bgS[128], bcS[10];
  u16* As = (u16*)smem;
  u16* Bs = (u16*)(smem + 32768);
  u16* Tb = (u16*)smem;  // reused after compute: [128][136] bf16
  int tid = threadIdx.x;
  for (int i = tid; i < 1280; i += 256) WcS[i] = Wcls[i];
  if (tid < 128) { hcS[tid] = hc[tid]; bgS[tid] = bg[tid]; }
  if (tid < 10) bcS[tid] = bcls[tid];
  int lane = tid & 63, wid = tid >> 6;
  int wm = wid & 1, wn = wid >> 1;
  int bRow = blockIdx.x * 128;

#pragma unroll
  for (int i = 0; i < 8; ++i) {
    int p = i * 256 + tid;
    int row = p >> 4, slot = p & 15, srs = slot ^ (row & 7);
    int gr = bRow + row; if (gr >= N) gr = N - 1;
    gload_lds16(Ab + (size_t)gr * 128 + srs * 8, (char*)As + p * 16);
    gload_lds16(W2T + (size_t)row * 128 + srs * 8, (char*)Bs + p * 16);
  }
  f32x4 acc[4][4];
#pragma unroll
  for (int mi = 0; mi < 4; ++mi)
#pragma unroll
    for (int ni = 0; ni < 4; ++ni) acc[mi][ni] = {0.f, 0.f, 0.f, 0.f};
  __syncthreads();
#pragma unroll
  for (int ks = 0; ks < 4; ++ks) {
    short8 af[4], bfv[4];
#pragma unroll
    for (int mi = 0; mi < 4; ++mi) {
      int row = wm * 64 + mi * 16 + (lane & 15);
      int swz = (ks * 4 + (lane >> 4)) ^ (lane & 7);
      af[mi] = *(const short8*)(As + row * 128 + swz * 8);
    }
#pragma unroll
    for (int ni = 0; ni < 4; ++ni) {
      int row = wn * 64 + ni * 16 + (lane & 15);
      int swz = (ks * 4 + (lane >> 4)) ^ (lane & 7);
      bfv[ni] = *(const short8*)(Bs + row * 128 + swz * 8);
    }
#pragma unroll
    for (int mi = 0; mi < 4; ++mi)
#pragma unroll
      for (int ni = 0; ni < 4; ++ni)
        acc[mi][ni] = __builtin_amdgcn_mfma_f32_16x16x32_bf16(af[mi], bfv[ni], acc[mi][ni], 0, 0, 0);
  }
  __syncthreads();

  float hcv[4], bgv[4];
#pragma unroll
  for (int ni = 0; ni < 4; ++ni) {
    int n = wn * 64 + ni * 16 + (lane & 15);
    hcv[ni] = hcS[n];
    bgv[ni] = bgS[n];
  }
#pragma unroll
  for (int mi = 0; mi < 4; ++mi) {
#pragma unroll
    for (int r = 0; r < 4; ++r) {
      int m = wm * 64 + mi * 16 + (lane >> 4) * 4 + r;
      int gr = bRow + m;
      float sc = (gr < N) ? scoef[gr] : 0.f;
#pragma unroll
      for (int ni = 0; ni < 4; ++ni) {
        float u = fmaxf(acc[mi][ni][r] + hcv[ni] * sc + bgv[ni], 0.f);
        Tb[m * 136 + wn * 64 + ni * 16 + (lane & 15)] = f2bf(u);
      }
    }
  }
  __syncthreads();

  int r2 = tid >> 1, qd = tid & 1;
  float part[10];
#pragma unroll
  for (int t = 0; t < 10; ++t) part[t] = 0.f;
  for (int jj = 0; jj < 64; ++jj) {
    int j = qd * 64 + jj;
    float a = bf2f(Tb[r2 * 136 + j]);
#pragma unroll
    for (int t = 0; t < 10; ++t) part[t] = fmaf(a, WcS[j * 10 + t], part[t]);
  }
#pragma unroll
  for (int t = 0; t < 10; ++t) part[t] += __shfl_xor(part[t], 1);
  int gr = bRow + r2;
  if (qd == 0 && gr < N) {
    float l[10], m = -1e30f;
#pragma unroll
    for (int t = 0; t < 10; ++t) {
      l[t] = part[t] + bcS[t];
      m = fmaxf(m, l[t]);
    }
    float se = 0.f;
#pragma unroll
    for (int t = 0; t < 10; ++t) se += expf(l[t] - m);
    float lse = m + logf(se);
#pragma unroll
    for (int t = 0; t < 10; ++t) out[(size_t)gr * 10 + t] = l[t] - lse;
  }
}

// ---------------------------------------------------------------------------
extern "C" void kernel_launch(void* const* d_in, const int* in_sizes, int n_in,
                              void* d_out, int out_size, void* d_ws, size_t ws_size,
                              hipStream_t stream) {
  const float* X = (const float*)d_in[0];
  const int* ei = (const int*)d_in[2];
  const float* gamma1 = (const float*)d_in[3];
  const float* beta1 = (const float*)d_in[4];
  const float* Wmlp = (const float*)d_in[5];
  const float* bmlp = (const float*)d_in[6];
  const float* gamma2 = (const float*)d_in[7];
  const float* beta2 = (const float*)d_in[8];
  const float* Wgcn = (const float*)d_in[9];
  const float* bgcn = (const float*)d_in[10];
  const float* Wcls = (const float*)d_in[11];
  const float* bcls = (const float*)d_in[12];
  float* out = (float*)d_out;

  const int N = in_sizes[0] / 512;
  const int E = in_sizes[2] / 2;
  const float invN = 1.0f / (float)N;

  char* ws = (char*)d_ws;
  float* s1 = (float*)(ws + 0);            // 512
  float* q1 = (float*)(ws + 2048);         // 512
  float* s2 = (float*)(ws + 4096);         // 128
  float* q2 = (float*)(ws + 4608);         // 128
  float* b1p = (float*)(ws + 5120);        // 128
  float* hconst = (float*)(ws + 5632);     // 128
  u16* W1bT = (u16*)(ws + 8192);           // 128*512 bf16
  u16* W2bT = (u16*)(ws + 139264);         // 128*128 bf16
  int* bsums = (int*)(ws + 172032);        // 256
  int* deg = (int*)(ws + 173056);          // N -> 373056
  int* offs = (int*)(ws + 373056);         // N -> 573056
  float* dinv = (float*)(ws + 573056);     // N -> 773056
  float* scoef = (float*)(ws + 773056);    // N -> 973056
  int* col = (int*)(ws + 973056);          // E -> 4173056
  int* epos = (int*)(ws + 4173056);        // E -> 7373056
  u16* Yb = (u16*)(ws + 7373056);          // N*128 bf16 -> 20173056
  u16* Ab = (u16*)(ws + 20173056);         // N*128 bf16 -> 32973056
  float* pS1 = (float*)(ws + 32973056);    // 1280*512 -> 35594496
  float* pQ1 = (float*)(ws + 35594496);    // 1280*512 -> 38215936
  float* pS2 = (float*)(ws + 38215936);    // 391*128 -> 38416128
  float* pQ2 = (float*)(ws + 38416128);    // 391*128 -> 38616320
  (void)ws_size; (void)n_in; (void)out_size;

  const int* esrc = ei;
  const int* edst = ei + E;
  int nb = (N + 255) / 256;   // 196
  int eb = (E + 255) / 256;   // 3125
  int gb = (N + 127) / 128;   // 391
  const int NBN = 1280;       // bn-stream blocks
  const int NEB = 768;        // degree blocks (grid-stride); NBN+NEB = 2048 = 1 residency

  // 1) zero stats+b1p+hconst (1536 floats) and deg (N ints)
  k_zero2<<<(1536 + N + 255) / 256, 256, 0, stream>>>(s1, 1536, (float*)deg, N);
  // 2) bn1 stats || degree count + epos record (co-resident)
  k_front<<<NBN + NEB, 256, 0, stream>>>(X, N, pS1, pQ1, edst, E, deg, epos, NBN, NEB);
  // 3) reduce bn1 partials || block-local scan
  k_mid1<<<16 + nb, 256, 0, stream>>>(pS1, pQ1, s1, q1, NBN, 80, deg, N, offs, bsums, dinv, 16);
  // 4) fold1 (WT + bias) || scan2
  k_mid2<<<272 + 1, 256, 0, stream>>>(s1, q1, gamma1, beta1, Wmlp, bmlp, W1bT, b1p,
                                      invN, 9, 256, 16, 32, bsums, nb);
  // 5) gemm1 (BM=128) || scatter (atomic-free)
  k_big<<<gb + eb, 256, 0, stream>>>(X, W1bT, b1p, Yb, pS2, pQ2, N,
                                     esrc, edst, E, offs, bsums, epos, col, gb);
  // 6) reduce gemm1 partials || gather
  k_agg<<<8 + (N + 3) / 4, 256, 0, stream>>>(pS2, pQ2, s2, q2, gb, (gb + 7) / 8,
                                             Yb, col, offs, bsums, deg, dinv, Ab, scoef, N, 8);
  // 7) fold2 (no scan part)
  k_mid2<<<72, 256, 0, stream>>>(s2, q2, gamma2, beta2, Wgcn, nullptr, W2bT, hconst,
                                 invN, 7, 64, 8, 16, nullptr, 0);
  // 8) final
  k_final<<<gb, 256, 0, stream>>>(Ab, W2bT, hconst, scoef, bgcn, Wcls, bcls, out, N);
}